// Round 2
// baseline (3370.693 us; speedup 1.0000x reference)
//
#include <hip/hip_runtime.h>

#define KNODES 4096
#define SEQL 32
#define DM 128
#define DFF 512
#define NEDGE 65536
#define NETOT (NEDGE + KNODES)

__device__ __forceinline__ float gelu_exact(float v) {
  return 0.5f * v * (1.f + erff(v * 0.70710678118654752440f));
}

// C[32][*] tile GEMM: acc[i][j] += sum_k A[r0+i][k] * W[tx+32j][k]
// A: LDS row-major (lda floats/row); W: global row-major (ldw floats/row).
// Caller zeros/keeps acc (FFN2 accumulates across K-chunks).
template<int KDIM, int JC>
__device__ __forceinline__ void mm_tile(const float* A, int lda,
                                        const float* __restrict__ W, int ldw,
                                        int tx, int ty, float (&acc)[4][JC]) {
  const int r0 = ty * 4;
  for (int k = 0; k < KDIM; k += 4) {
    float4 a[4];
#pragma unroll
    for (int i = 0; i < 4; ++i)
      a[i] = *(const float4*)(A + (r0 + i) * lda + k);
    float4 w[JC];
#pragma unroll
    for (int j = 0; j < JC; ++j)
      w[j] = *(const float4*)(W + (tx + 32 * j) * ldw + k);
#pragma unroll
    for (int i = 0; i < 4; ++i)
#pragma unroll
      for (int j = 0; j < JC; ++j)
        acc[i][j] += a[i].x * w[j].x + a[i].y * w[j].y +
                     a[i].z * w[j].z + a[i].w * w[j].w;
  }
}

// LayerNorm rows of X[32][128] -> H[32][128]; 8 threads per row.
__device__ __forceinline__ void layernorm(const float* X, float* H,
                                          const float* __restrict__ g,
                                          const float* __restrict__ b,
                                          int t, float* redA, float* redB) {
  const int r = t >> 3, q = t & 7;
  const float* xr = X + r * DM + q * 16;
  float s = 0.f, ss = 0.f;
#pragma unroll
  for (int i = 0; i < 16; ++i) { float v = xr[i]; s += v; ss += v * v; }
  redA[r * 8 + q] = s; redB[r * 8 + q] = ss;
  __syncthreads();
  float S = 0.f, SS = 0.f;
#pragma unroll
  for (int i = 0; i < 8; ++i) { S += redA[r * 8 + i]; SS += redB[r * 8 + i]; }
  const float mean = S * (1.f / 128.f);
  const float var = SS * (1.f / 128.f) - mean * mean;
  const float rs = rsqrtf(var + 1e-5f);
  float* hr = H + r * DM + q * 16;
  const float* gr = g + q * 16;
  const float* br = b + q * 16;
#pragma unroll
  for (int i = 0; i < 16; ++i) hr[i] = (xr[i] - mean) * rs * gr[i] + br[i];
  __syncthreads();
}

// One block per node: full temporal transformer layer + GAT projection h,
// plus per-(node,l) attention scalars a_s, a_d. xt never goes to global.
__global__ __launch_bounds__(256, 2) void temporal_kernel(
    const float* __restrict__ x,
    const float* __restrict__ ln1_g, const float* __restrict__ ln1_b,
    const float* __restrict__ qkv_w, const float* __restrict__ qkv_b,
    const float* __restrict__ out_w, const float* __restrict__ out_b,
    const float* __restrict__ ln2_g, const float* __restrict__ ln2_b,
    const float* __restrict__ ff1_w, const float* __restrict__ ff1_b,
    const float* __restrict__ ff2_w, const float* __restrict__ ff2_b,
    const float* __restrict__ gat_w,
    const float* __restrict__ att_src, const float* __restrict__ att_dst,
    float* __restrict__ h_out, float* __restrict__ as_out, float* __restrict__ ad_out) {
  __shared__ __align__(16) float Xs[SEQL * DM];    // residual x, 16 KB
  __shared__ __align__(16) float Hs[SEQL * DM];    // normed h, 16 KB
  __shared__ __align__(16) float Buf[SEQL * 256];  // Q|K / V|attn / FFN chunk, 32 KB
  __shared__ __align__(16) float Ss[SEQL * SEQL];  // scores, 4 KB
  __shared__ float redA[SEQL * 8], redB[SEQL * 8];

  const int t = threadIdx.x;
  const int tx = t & 31, ty = t >> 5;
  const int n = blockIdx.x;
  const float* xg = x + (size_t)n * (SEQL * DM);

  // load x -> Xs (coalesced float4)
  {
    const float4* s4 = (const float4*)xg;
    float4* d4 = (float4*)Xs;
    for (int i = t; i < SEQL * DM / 4; i += 256) d4[i] = s4[i];
  }
  __syncthreads();

  layernorm(Xs, Hs, ln1_g, ln1_b, t, redA, redB);

  // Q,K GEMM (qkv_w rows 0..255) -> Buf rows stride 256 (cols 0..127=Q, 128..255=K)
  {
    float acc[4][8];
#pragma unroll
    for (int i = 0; i < 4; ++i)
#pragma unroll
      for (int j = 0; j < 8; ++j) acc[i][j] = 0.f;
    mm_tile<DM, 8>(Hs, DM, qkv_w, DM, tx, ty, acc);
#pragma unroll
    for (int i = 0; i < 4; ++i)
#pragma unroll
      for (int j = 0; j < 8; ++j) {
        int c = tx + 32 * j;
        Buf[(ty * 4 + i) * 256 + c] = acc[i][j] + qkv_b[c];
      }
  }
  __syncthreads();

  // S = Q K^T / sqrt(D)
  {
    const int i = t >> 3, j0 = t & 7;
#pragma unroll
    for (int m = 0; m < 4; ++m) {
      const int jj = j0 + 8 * m;
      float s = 0.f;
      const float4* q4 = (const float4*)(Buf + i * 256);
      const float4* k4 = (const float4*)(Buf + jj * 256 + 128);
#pragma unroll
      for (int d = 0; d < 32; ++d) {
        float4 qa = q4[d], kb = k4[d];
        s += qa.x * kb.x + qa.y * kb.y + qa.z * kb.z + qa.w * kb.w;
      }
      Ss[i * 32 + jj] = s * 0.08838834764831845f;  // 1/sqrt(128)
    }
  }
  __syncthreads();

  // softmax rows (serial per row, 32 rows)
  if (t < SEQL) {
    float mx = -3.4e38f;
    for (int j = 0; j < 32; ++j) mx = fmaxf(mx, Ss[t * 32 + j]);
    float sum = 0.f;
    for (int j = 0; j < 32; ++j) { float e = expf(Ss[t * 32 + j] - mx); Ss[t * 32 + j] = e; sum += e; }
    const float inv = 1.f / sum;
    for (int j = 0; j < 32; ++j) Ss[t * 32 + j] *= inv;
  }
  __syncthreads();

  // V GEMM (qkv_w rows 256..383) -> Buf[0..4095] stride 128
  {
    float acc[4][4];
#pragma unroll
    for (int i = 0; i < 4; ++i)
#pragma unroll
      for (int j = 0; j < 4; ++j) acc[i][j] = 0.f;
    mm_tile<DM, 4>(Hs, DM, qkv_w + 256 * DM, DM, tx, ty, acc);
#pragma unroll
    for (int i = 0; i < 4; ++i)
#pragma unroll
      for (int j = 0; j < 4; ++j) {
        int c = tx + 32 * j;
        Buf[(ty * 4 + i) * DM + c] = acc[i][j] + qkv_b[256 + c];
      }
  }
  __syncthreads();

  // attn = S @ V -> Buf[4096..8191] stride 128
  {
    const int r = t >> 3, d0 = (t & 7) * 16;
    float4 acc4[4];
#pragma unroll
    for (int m = 0; m < 4; ++m) acc4[m] = make_float4(0.f, 0.f, 0.f, 0.f);
    for (int j = 0; j < 32; ++j) {
      const float s = Ss[r * 32 + j];
      const float4* vrow = (const float4*)(Buf + j * DM + d0);
#pragma unroll
      for (int m = 0; m < 4; ++m) {
        float4 v = vrow[m];
        acc4[m].x += s * v.x; acc4[m].y += s * v.y;
        acc4[m].z += s * v.z; acc4[m].w += s * v.w;
      }
    }
    float4* o = (float4*)(Buf + 4096 + r * DM + d0);
#pragma unroll
    for (int m = 0; m < 4; ++m) o[m] = acc4[m];
  }
  __syncthreads();

  // proj: Xs += attn @ out_w^T + out_b
  {
    float acc[4][4];
#pragma unroll
    for (int i = 0; i < 4; ++i)
#pragma unroll
      for (int j = 0; j < 4; ++j) acc[i][j] = 0.f;
    mm_tile<DM, 4>(Buf + 4096, DM, out_w, DM, tx, ty, acc);
#pragma unroll
    for (int i = 0; i < 4; ++i)
#pragma unroll
      for (int j = 0; j < 4; ++j) {
        int c = tx + 32 * j, r = ty * 4 + i;
        Xs[r * DM + c] += acc[i][j] + out_b[c];
      }
  }
  __syncthreads();

  layernorm(Xs, Hs, ln2_g, ln2_b, t, redA, redB);

  // FFN in two 256-col chunks: F_chunk = gelu(Hs@ff1^T) in Buf, then partial FFN2
  {
    float facc[4][4];
#pragma unroll
    for (int i = 0; i < 4; ++i)
#pragma unroll
      for (int j = 0; j < 4; ++j) facc[i][j] = 0.f;
    for (int ch = 0; ch < 2; ++ch) {
      float acc[4][8];
#pragma unroll
      for (int i = 0; i < 4; ++i)
#pragma unroll
        for (int j = 0; j < 8; ++j) acc[i][j] = 0.f;
      mm_tile<DM, 8>(Hs, DM, ff1_w + ch * 256 * DM, DM, tx, ty, acc);
      __syncthreads();  // previous chunk's Buf reads (FFN2) complete
#pragma unroll
      for (int i = 0; i < 4; ++i)
#pragma unroll
        for (int j = 0; j < 8; ++j) {
          int c = tx + 32 * j;
          Buf[(ty * 4 + i) * 256 + c] = gelu_exact(acc[i][j] + ff1_b[ch * 256 + c]);
        }
      __syncthreads();
      mm_tile<256, 4>(Buf, 256, ff2_w + ch * 256, DFF, tx, ty, facc);  // accumulates
    }
    __syncthreads();
#pragma unroll
    for (int i = 0; i < 4; ++i)
#pragma unroll
      for (int j = 0; j < 4; ++j) {
        int c = tx + 32 * j, r = ty * 4 + i;
        Xs[r * DM + c] += facc[i][j] + ff2_b[c];
      }
  }
  __syncthreads();

  // GAT projection: hmat = xt @ gat_w^T -> Buf[0..4095] + global h_out
  {
    float acc[4][4];
#pragma unroll
    for (int i = 0; i < 4; ++i)
#pragma unroll
      for (int j = 0; j < 4; ++j) acc[i][j] = 0.f;
    mm_tile<DM, 4>(Xs, DM, gat_w, DM, tx, ty, acc);
#pragma unroll
    for (int i = 0; i < 4; ++i)
#pragma unroll
      for (int j = 0; j < 4; ++j) {
        int c = tx + 32 * j, r = ty * 4 + i;
        Buf[r * DM + c] = acc[i][j];
        h_out[((size_t)n * SEQL + r) * DM + c] = acc[i][j];
      }
  }
  __syncthreads();

  // a_s[l] = h[l]·att_src, a_d[l] = h[l]·att_dst
  if (t < 2 * SEQL) {
    const int row = t & 31;
    const float* vec = (t < SEQL) ? att_src : att_dst;
    float s = 0.f;
    for (int d = 0; d < DM; ++d) s += Buf[row * DM + d] * vec[d];
    if (t < SEQL) as_out[n * SEQL + row] = s;
    else          ad_out[n * SEQL + row] = s;
  }
}

__global__ void zero_counts(int* counts) {
  int i = blockIdx.x * 256 + threadIdx.x;
  if (i < KNODES) counts[i] = 0;
}

// edge_index delivered as int32 by the harness (integer inputs -> const int*)
__global__ void hist_kernel(const int* __restrict__ ei, int* counts) {
  int i = blockIdx.x * 256 + threadIdx.x;
  if (i < NETOT) {
    int dst = (i < NEDGE) ? ei[NEDGE + i] : (i - NEDGE);
    atomicAdd(&counts[dst], 1);
  }
}

// single-block exclusive scan of 4096 counts (1024 thr x 4)
__global__ void scan_kernel(const int* __restrict__ counts, int* offs, int* cursor) {
  __shared__ int tmp[1024];
  const int t = threadIdx.x;
  const int base = t * 4;
  int c0 = counts[base], c1 = counts[base + 1], c2 = counts[base + 2], c3 = counts[base + 3];
  const int s = c0 + c1 + c2 + c3;
  tmp[t] = s;
  __syncthreads();
  for (int off = 1; off < 1024; off <<= 1) {
    int v = (t >= off) ? tmp[t - off] : 0;
    __syncthreads();
    tmp[t] += v;
    __syncthreads();
  }
  int o = tmp[t] - s;  // exclusive
  offs[base] = o; cursor[base] = o; o += c0;
  offs[base + 1] = o; cursor[base + 1] = o; o += c1;
  offs[base + 2] = o; cursor[base + 2] = o; o += c2;
  offs[base + 3] = o; cursor[base + 3] = o; o += c3;
  if (t == 1023) offs[KNODES] = o;
}

__global__ void scatter_kernel(const int* __restrict__ ei, int* cursor, int* __restrict__ csr) {
  int i = blockIdx.x * 256 + threadIdx.x;
  if (i < NETOT) {
    int src, dst;
    if (i < NEDGE) { src = ei[i]; dst = ei[NEDGE + i]; }
    else           { src = dst = i - NEDGE; }
    int pos = atomicAdd(&cursor[dst], 1);
    csr[pos] = src;
  }
}

// One block per destination node: softmax over incoming edges + weighted sum.
__global__ __launch_bounds__(256) void gat_aggregate(
    const float* __restrict__ h, const float* __restrict__ as_g, const float* __restrict__ ad_g,
    const int* __restrict__ offs, const int* __restrict__ csr,
    const float* __restrict__ gat_b, float* __restrict__ out) {
  __shared__ float ad_s[SEQL];
  __shared__ float denom[SEQL];
  const int t = threadIdx.x;
  const int n = blockIdx.x;
  if (t < SEQL) { ad_s[t] = ad_g[n * SEQL + t]; denom[t] = 0.f; }
  __syncthreads();
  const int beg = offs[n], end = offs[n + 1];

  // pass 1: denominators (8 edges x 32 l per iteration)
  for (int e0 = beg; e0 < end; e0 += 8) {
    const int e = e0 + (t >> 5);
    if (e < end) {
      const int src = csr[e];
      const int l = t & 31;
      float v = as_g[src * SEQL + l] + ad_s[l];
      v = v > 0.f ? v : 0.2f * v;
      atomicAdd(&denom[l], expf(v));
    }
  }
  __syncthreads();

  // pass 2: out[n,l,d] = sum_e alpha * h[src,l,d]
  const int d = t & 127, lh = t >> 7;  // lh in {0,1}; thread owns l = lh*16+j
  float acc[16], invd[16], adv[16];
#pragma unroll
  for (int j = 0; j < 16; ++j) {
    acc[j] = 0.f;
    invd[j] = 1.f / (denom[lh * 16 + j] + 1e-16f);
    adv[j] = ad_s[lh * 16 + j];
  }
  for (int e = beg; e < end; ++e) {
    const int src = csr[e];
    const float* hrow = h + (size_t)src * (SEQL * DM) + d;
    const float* asrow = as_g + src * SEQL;
#pragma unroll
    for (int j = 0; j < 16; ++j) {
      const int l = lh * 16 + j;
      float v = asrow[l] + adv[j];
      v = v > 0.f ? v : 0.2f * v;
      acc[j] += expf(v) * invd[j] * hrow[l * DM];
    }
  }
  const float bd = gat_b[d];
#pragma unroll
  for (int j = 0; j < 16; ++j)
    out[(size_t)n * (SEQL * DM) + (lh * 16 + j) * DM + d] = acc[j] + bd;
}

extern "C" void kernel_launch(void* const* d_in, const int* in_sizes, int n_in,
                              void* d_out, int out_size, void* d_ws, size_t ws_size,
                              hipStream_t stream) {
  const float* x       = (const float*)d_in[0];
  const int* ei        = (const int*)d_in[1];   // int32 per harness contract
  const float* ln1_g   = (const float*)d_in[2];
  const float* ln1_b   = (const float*)d_in[3];
  const float* qkv_w   = (const float*)d_in[4];
  const float* qkv_b   = (const float*)d_in[5];
  const float* out_w   = (const float*)d_in[6];
  const float* out_b   = (const float*)d_in[7];
  const float* ln2_g   = (const float*)d_in[8];
  const float* ln2_b   = (const float*)d_in[9];
  const float* ff1_w   = (const float*)d_in[10];
  const float* ff1_b   = (const float*)d_in[11];
  const float* ff2_w   = (const float*)d_in[12];
  const float* ff2_b   = (const float*)d_in[13];
  const float* gat_w   = (const float*)d_in[14];
  const float* att_src = (const float*)d_in[15];
  const float* att_dst = (const float*)d_in[16];
  const float* gat_b   = (const float*)d_in[17];
  float* out = (float*)d_out;

  // workspace layout
  float* h    = (float*)d_ws;                     // 4096*32*128 = 16777216 floats
  float* as_g = h + (size_t)KNODES * SEQL * DM;   // 131072
  float* ad_g = as_g + KNODES * SEQL;             // 131072
  int* counts = (int*)(ad_g + KNODES * SEQL);     // 4096
  int* offs   = counts + KNODES;                  // 4097
  int* cursor = offs + KNODES + 1;                // 4096
  int* csr    = cursor + KNODES;                  // 69632

  temporal_kernel<<<KNODES, 256, 0, stream>>>(
      x, ln1_g, ln1_b, qkv_w, qkv_b, out_w, out_b, ln2_g, ln2_b,
      ff1_w, ff1_b, ff2_w, ff2_b, gat_w, att_src, att_dst, h, as_g, ad_g);
  zero_counts<<<(KNODES + 255) / 256, 256, 0, stream>>>(counts);
  hist_kernel<<<(NETOT + 255) / 256, 256, 0, stream>>>(ei, counts);
  scan_kernel<<<1, 1024, 0, stream>>>(counts, offs, cursor);
  scatter_kernel<<<(NETOT + 255) / 256, 256, 0, stream>>>(ei, cursor, csr);
  gat_aggregate<<<KNODES, 256, 0, stream>>>(h, as_g, ad_g, offs, csr, gat_b, out);
}

// Round 3
// 589.678 us; speedup vs baseline: 5.7162x; 5.7162x over previous
//
#include <hip/hip_runtime.h>

#define KNODES 4096
#define SEQL 32
#define DM 128
#define DFF 512
#define NEDGE 65536
#define NETOT (NEDGE + KNODES)

typedef float f32x4 __attribute__((ext_vector_type(4)));
typedef short s16x8 __attribute__((ext_vector_type(8)));
typedef short s16x4 __attribute__((ext_vector_type(4)));

#define MFMA16(a, b, c) __builtin_amdgcn_mfma_f32_16x16x32_bf16(a, b, c, 0, 0, 0)

__device__ __forceinline__ short f2bf(float f) {
  union { float f; unsigned u; } v; v.f = f;
  unsigned r = (v.u + 0x7FFFu + ((v.u >> 16) & 1u)) >> 16;
  return (short)r;
}

__device__ __forceinline__ float gelu_exact(float v) {
  return 0.5f * v * (1.f + erff(v * 0.70710678118654752440f));
}

// LayerNorm XF[32][132] fp32 -> AB[32][136] bf16. 8 lanes per row (consecutive).
__device__ __forceinline__ void ln_to_bf16(const float* XF, short* AB,
                                           const float* __restrict__ g,
                                           const float* __restrict__ b,
                                           int r8, int c16) {
  const float* xr = XF + r8 * 132 + c16;
  float v[16]; float s = 0.f, ss = 0.f;
#pragma unroll
  for (int i = 0; i < 16; ++i) { v[i] = xr[i]; s += v[i]; ss += v[i] * v[i]; }
  s += __shfl_xor(s, 1); ss += __shfl_xor(ss, 1);
  s += __shfl_xor(s, 2); ss += __shfl_xor(ss, 2);
  s += __shfl_xor(s, 4); ss += __shfl_xor(ss, 4);
  const float mean = s * (1.f / 128.f);
  const float var = ss * (1.f / 128.f) - mean * mean;
  const float rs = rsqrtf(var + 1e-5f);
  const float* gp = g + c16; const float* bp = b + c16;
  short o[16];
#pragma unroll
  for (int i = 0; i < 16; ++i) o[i] = f2bf((v[i] - mean) * rs * gp[i] + bp[i]);
  s16x8* dst = (s16x8*)(AB + r8 * 136 + c16);
  dst[0] = *(s16x8*)o; dst[1] = *(s16x8*)(o + 8);
}

// LDS map (bytes), total 53248 -> 3 blocks/CU:
//  XF  @0      fp32 [32][132]  residual / h scratch        (16896)
//  AB  @16896  bf16 [32][136]  LN out / xt bf16            (8704)   } aliased by
//  Sf  @16896  fp32 [32][36]   scores                      (4608)   } S+P after
//  Pb  @21504  bf16 [32][40]   probs (A-layout)            (2560)   } QKV phase
//  Qb  @25600  bf16 [32][136]  Q, then attn                (8704)   } aliased by
//  Kb  @34304  bf16 [32][136]  K                           (8704)   } Fb (FFN)
//  Fb  @25600  bf16 [32][264]  gelu(FFN1) chunk            (16896)
//  Vt  @43008  bf16 [128][40]  V transposed (B-layout)     (10240)
__global__ __launch_bounds__(256, 3) void temporal_kernel(
    const float* __restrict__ x,
    const float* __restrict__ ln1_g, const float* __restrict__ ln1_b,
    const short* __restrict__ qkv_wb, const float* __restrict__ qkv_b,
    const short* __restrict__ out_wb, const float* __restrict__ out_b,
    const float* __restrict__ ln2_g, const float* __restrict__ ln2_b,
    const short* __restrict__ ff1_wb, const float* __restrict__ ff1_b,
    const short* __restrict__ ff2_wb, const float* __restrict__ ff2_b,
    const short* __restrict__ gat_wb,
    const float* __restrict__ att_src, const float* __restrict__ att_dst,
    float* __restrict__ h_out, float* __restrict__ as_out, float* __restrict__ ad_out) {
  __shared__ __align__(16) char smem[53248];
  float* XF = (float*)smem;
  short* AB = (short*)(smem + 16896);
  float* Sf = (float*)(smem + 16896);
  short* Pb = (short*)(smem + 21504);
  short* Qb = (short*)(smem + 25600);
  short* Kb = (short*)(smem + 34304);
  short* Fb = (short*)(smem + 25600);
  short* Vt = (short*)(smem + 43008);

  const int t = threadIdx.x;
  const int w = t >> 6;
  const int lane = t & 63;
  const int q = lane >> 4, c = lane & 15;
  const int n = blockIdx.x;
  const int r8 = t >> 3, c16 = (t & 7) * 16, c4 = (t & 7) * 4;

  // ---- load x -> XF (fp32)
  {
    const float4* s4 = (const float4*)(x + (size_t)n * (SEQL * DM) + r8 * DM + c16);
    float4* d4 = (float4*)(XF + r8 * 132 + c16);
    d4[0] = s4[0]; d4[1] = s4[1]; d4[2] = s4[2]; d4[3] = s4[3];
  }
  __syncthreads();

  // ---- LN1 -> AB
  ln_to_bf16(XF, AB, ln1_g, ln1_b, r8, c16);
  __syncthreads();

  // ---- QKV GEMM: [32x128] @ [128x384]^T. 24 N-tiles, 6 per wave.
  {
    s16x8 a[2][4];
#pragma unroll
    for (int mt = 0; mt < 2; ++mt)
#pragma unroll
      for (int kt = 0; kt < 4; ++kt)
        a[mt][kt] = *(const s16x8*)(AB + (mt * 16 + c) * 136 + kt * 32 + q * 8);
    for (int ii = 0; ii < 6; ++ii) {
      const int n0 = (w * 6 + ii) * 16;
      const short* wp = qkv_wb + (n0 + c) * DM + q * 8;
      s16x8 bf[4];
#pragma unroll
      for (int kt = 0; kt < 4; ++kt) bf[kt] = *(const s16x8*)(wp + kt * 32);
      f32x4 acc0 = {0.f, 0.f, 0.f, 0.f}, acc1 = {0.f, 0.f, 0.f, 0.f};
#pragma unroll
      for (int kt = 0; kt < 4; ++kt) {
        acc0 = MFMA16(a[0][kt], bf[kt], acc0);
        acc1 = MFMA16(a[1][kt], bf[kt], acc1);
      }
      const float bias = qkv_b[n0 + c];
      if (n0 < 128) {            // Q -> Qb row-major
#pragma unroll
        for (int i = 0; i < 4; ++i) {
          Qb[(q * 4 + i) * 136 + n0 + c] = f2bf(acc0[i] + bias);
          Qb[(16 + q * 4 + i) * 136 + n0 + c] = f2bf(acc1[i] + bias);
        }
      } else if (n0 < 256) {     // K -> Kb row-major
        const int cc = n0 - 128 + c;
#pragma unroll
        for (int i = 0; i < 4; ++i) {
          Kb[(q * 4 + i) * 136 + cc] = f2bf(acc0[i] + bias);
          Kb[(16 + q * 4 + i) * 136 + cc] = f2bf(acc1[i] + bias);
        }
      } else {                   // V -> Vt[d][j] transposed (packed b64 writes)
        const int d = n0 - 256 + c;
        s16x4 p0, p1;
#pragma unroll
        for (int i = 0; i < 4; ++i) { p0[i] = f2bf(acc0[i] + bias); p1[i] = f2bf(acc1[i] + bias); }
        *(s16x4*)(Vt + d * 40 + q * 4) = p0;
        *(s16x4*)(Vt + d * 40 + 16 + q * 4) = p1;
      }
    }
  }
  __syncthreads();

  // ---- scores S = Q K^T / sqrt(128). One 16x16 tile per wave.
  {
    const int mt = w & 1, nt = w >> 1;
    s16x8 aq[4], bk[4];
#pragma unroll
    for (int kt = 0; kt < 4; ++kt) {
      aq[kt] = *(const s16x8*)(Qb + (mt * 16 + c) * 136 + kt * 32 + q * 8);
      bk[kt] = *(const s16x8*)(Kb + (nt * 16 + c) * 136 + kt * 32 + q * 8);
    }
    f32x4 acc = {0.f, 0.f, 0.f, 0.f};
#pragma unroll
    for (int kt = 0; kt < 4; ++kt) acc = MFMA16(aq[kt], bk[kt], acc);
#pragma unroll
    for (int i = 0; i < 4; ++i)
      Sf[(mt * 16 + q * 4 + i) * 36 + nt * 16 + c] = acc[i] * 0.08838834764831845f;
  }
  __syncthreads();

  // ---- softmax rows of Sf -> Pb (bf16, A-layout ready)
  {
    float4 sv = *(const float4*)(Sf + r8 * 36 + c4);
    float mx = fmaxf(fmaxf(sv.x, sv.y), fmaxf(sv.z, sv.w));
    mx = fmaxf(mx, __shfl_xor(mx, 1));
    mx = fmaxf(mx, __shfl_xor(mx, 2));
    mx = fmaxf(mx, __shfl_xor(mx, 4));
    float e0 = expf(sv.x - mx), e1 = expf(sv.y - mx), e2 = expf(sv.z - mx), e3 = expf(sv.w - mx);
    float sum = e0 + e1 + e2 + e3;
    sum += __shfl_xor(sum, 1);
    sum += __shfl_xor(sum, 2);
    sum += __shfl_xor(sum, 4);
    const float inv = 1.f / sum;
    s16x4 pw; pw[0] = f2bf(e0 * inv); pw[1] = f2bf(e1 * inv); pw[2] = f2bf(e2 * inv); pw[3] = f2bf(e3 * inv);
    *(s16x4*)(Pb + r8 * 40 + c4) = pw;
  }
  __syncthreads();

  // ---- attn = P @ V  (K=32, one k-tile). 2 d-tiles per wave -> Qb (attn).
  {
    s16x8 ap0 = *(const s16x8*)(Pb + c * 40 + q * 8);
    s16x8 ap1 = *(const s16x8*)(Pb + (16 + c) * 40 + q * 8);
#pragma unroll
    for (int ii = 0; ii < 2; ++ii) {
      const int d0 = (w * 2 + ii) * 16;
      s16x8 bv = *(const s16x8*)(Vt + (d0 + c) * 40 + q * 8);
      f32x4 acc0 = {0.f, 0.f, 0.f, 0.f}, acc1 = {0.f, 0.f, 0.f, 0.f};
      acc0 = MFMA16(ap0, bv, acc0);
      acc1 = MFMA16(ap1, bv, acc1);
#pragma unroll
      for (int i = 0; i < 4; ++i) {
        Qb[(q * 4 + i) * 136 + d0 + c] = f2bf(acc0[i]);
        Qb[(16 + q * 4 + i) * 136 + d0 + c] = f2bf(acc1[i]);
      }
    }
  }
  __syncthreads();

  // ---- proj: XF += attn @ out_w^T + out_b
  {
    s16x8 aa[2][4];
#pragma unroll
    for (int mt = 0; mt < 2; ++mt)
#pragma unroll
      for (int kt = 0; kt < 4; ++kt)
        aa[mt][kt] = *(const s16x8*)(Qb + (mt * 16 + c) * 136 + kt * 32 + q * 8);
#pragma unroll
    for (int ii = 0; ii < 2; ++ii) {
      const int n0 = (w * 2 + ii) * 16;
      const short* wp = out_wb + (n0 + c) * DM + q * 8;
      s16x8 bf[4];
#pragma unroll
      for (int kt = 0; kt < 4; ++kt) bf[kt] = *(const s16x8*)(wp + kt * 32);
      f32x4 acc0 = {0.f, 0.f, 0.f, 0.f}, acc1 = {0.f, 0.f, 0.f, 0.f};
#pragma unroll
      for (int kt = 0; kt < 4; ++kt) {
        acc0 = MFMA16(aa[0][kt], bf[kt], acc0);
        acc1 = MFMA16(aa[1][kt], bf[kt], acc1);
      }
      const float bias = out_b[n0 + c];
#pragma unroll
      for (int i = 0; i < 4; ++i) {
        XF[(q * 4 + i) * 132 + n0 + c] += acc0[i] + bias;
        XF[(16 + q * 4 + i) * 132 + n0 + c] += acc1[i] + bias;
      }
    }
  }
  __syncthreads();

  // ---- LN2 -> AB
  ln_to_bf16(XF, AB, ln2_g, ln2_b, r8, c16);
  __syncthreads();

  // ---- FFN (two 256-col chunks through Fb), FFN2 accumulates in regs
  {
    s16x8 af[2][4];
#pragma unroll
    for (int mt = 0; mt < 2; ++mt)
#pragma unroll
      for (int kt = 0; kt < 4; ++kt)
        af[mt][kt] = *(const s16x8*)(AB + (mt * 16 + c) * 136 + kt * 32 + q * 8);
    f32x4 facc[2][2];
#pragma unroll
    for (int mt = 0; mt < 2; ++mt)
#pragma unroll
      for (int ii = 0; ii < 2; ++ii) facc[mt][ii] = (f32x4){0.f, 0.f, 0.f, 0.f};

    for (int ch = 0; ch < 2; ++ch) {
      // FFN1: 4 n-tiles per wave -> gelu -> Fb
#pragma unroll
      for (int ii = 0; ii < 4; ++ii) {
        const int ntl = w * 4 + ii;            // chunk-local tile 0..15
        const int n0g = ch * 256 + ntl * 16;   // global ff1 row
        const short* wp = ff1_wb + (n0g + c) * DM + q * 8;
        s16x8 bf[4];
#pragma unroll
        for (int kt = 0; kt < 4; ++kt) bf[kt] = *(const s16x8*)(wp + kt * 32);
        f32x4 acc0 = {0.f, 0.f, 0.f, 0.f}, acc1 = {0.f, 0.f, 0.f, 0.f};
#pragma unroll
        for (int kt = 0; kt < 4; ++kt) {
          acc0 = MFMA16(af[0][kt], bf[kt], acc0);
          acc1 = MFMA16(af[1][kt], bf[kt], acc1);
        }
        const float bias = ff1_b[n0g + c];
#pragma unroll
        for (int i = 0; i < 4; ++i) {
          Fb[(q * 4 + i) * 264 + ntl * 16 + c] = f2bf(gelu_exact(acc0[i] + bias));
          Fb[(16 + q * 4 + i) * 264 + ntl * 16 + c] = f2bf(gelu_exact(acc1[i] + bias));
        }
      }
      __syncthreads();
      // FFN2 partial over this chunk's K=256
      {
        s16x8 a2[2][8];
#pragma unroll
        for (int mt = 0; mt < 2; ++mt)
#pragma unroll
          for (int kt = 0; kt < 8; ++kt)
            a2[mt][kt] = *(const s16x8*)(Fb + (mt * 16 + c) * 264 + kt * 32 + q * 8);
#pragma unroll
        for (int ii = 0; ii < 2; ++ii) {
          const int n0 = (w * 2 + ii) * 16;
          const short* wp = ff2_wb + (n0 + c) * DFF + ch * 256 + q * 8;
#pragma unroll
          for (int kt = 0; kt < 8; ++kt) {
            s16x8 bf = *(const s16x8*)(wp + kt * 32);
            facc[0][ii] = MFMA16(a2[0][kt], bf, facc[0][ii]);
            facc[1][ii] = MFMA16(a2[1][kt], bf, facc[1][ii]);
          }
        }
      }
      __syncthreads();
    }
    // epilogue: XF += facc + ff2_b
#pragma unroll
    for (int ii = 0; ii < 2; ++ii) {
      const int n0 = (w * 2 + ii) * 16;
      const float bias = ff2_b[n0 + c];
#pragma unroll
      for (int i = 0; i < 4; ++i) {
        XF[(q * 4 + i) * 132 + n0 + c] += facc[0][ii][i] + bias;
        XF[(16 + q * 4 + i) * 132 + n0 + c] += facc[1][ii][i] + bias;
      }
    }
  }
  __syncthreads();

  // ---- xt -> bf16 (AB), no norm
  {
    const float* xr = XF + r8 * 132 + c16;
    short o[16];
#pragma unroll
    for (int i = 0; i < 16; ++i) o[i] = f2bf(xr[i]);
    s16x8* dst = (s16x8*)(AB + r8 * 136 + c16);
    dst[0] = *(s16x8*)o; dst[1] = *(s16x8*)(o + 8);
  }
  __syncthreads();

  // ---- GAT projection h = xt @ gat_w^T -> global h_out (fp32) + XF scratch
  {
    s16x8 ag[2][4];
#pragma unroll
    for (int mt = 0; mt < 2; ++mt)
#pragma unroll
      for (int kt = 0; kt < 4; ++kt)
        ag[mt][kt] = *(const s16x8*)(AB + (mt * 16 + c) * 136 + kt * 32 + q * 8);
#pragma unroll
    for (int ii = 0; ii < 2; ++ii) {
      const int n0 = (w * 2 + ii) * 16;
      const short* wp = gat_wb + (n0 + c) * DM + q * 8;
      s16x8 bf[4];
#pragma unroll
      for (int kt = 0; kt < 4; ++kt) bf[kt] = *(const s16x8*)(wp + kt * 32);
      f32x4 acc0 = {0.f, 0.f, 0.f, 0.f}, acc1 = {0.f, 0.f, 0.f, 0.f};
#pragma unroll
      for (int kt = 0; kt < 4; ++kt) {
        acc0 = MFMA16(ag[0][kt], bf[kt], acc0);
        acc1 = MFMA16(ag[1][kt], bf[kt], acc1);
      }
#pragma unroll
      for (int i = 0; i < 4; ++i) {
        const int r0 = q * 4 + i, r1 = 16 + q * 4 + i;
        h_out[((size_t)n * SEQL + r0) * DM + n0 + c] = acc0[i];
        h_out[((size_t)n * SEQL + r1) * DM + n0 + c] = acc1[i];
        XF[r0 * 132 + n0 + c] = acc0[i];
        XF[r1 * 132 + n0 + c] = acc1[i];
      }
    }
  }
  __syncthreads();

  // ---- a_s / a_d
  if (t < 64) {
    const int row = t & 31;
    const float* vec = (t < 32) ? att_src : att_dst;
    const float* hr = XF + row * 132;
    float s = 0.f;
#pragma unroll
    for (int d = 0; d < DM; d += 4)
      s += hr[d] * vec[d] + hr[d + 1] * vec[d + 1] + hr[d + 2] * vec[d + 2] + hr[d + 3] * vec[d + 3];
    if (t < 32) as_out[n * SEQL + row] = s;
    else        ad_out[n * SEQL + row] = s;
  }
}

// fp32 -> bf16 weight conversion, all 5 arrays into one contiguous buffer.
__global__ void cvt_weights(const float* __restrict__ qkv_w, const float* __restrict__ out_w,
                            const float* __restrict__ ff1_w, const float* __restrict__ ff2_w,
                            const float* __restrict__ gat_w, short* __restrict__ wb) {
  const int i = (blockIdx.x * 256 + threadIdx.x) * 4;
  if (i >= 212992) return;
  const float* src; int off;
  if (i < 49152)       { src = qkv_w; off = i; }
  else if (i < 65536)  { src = out_w; off = i - 49152; }
  else if (i < 131072) { src = ff1_w; off = i - 65536; }
  else if (i < 196608) { src = ff2_w; off = i - 131072; }
  else                 { src = gat_w; off = i - 196608; }
  const float4 v = *(const float4*)(src + off);
  s16x4 o; o[0] = f2bf(v.x); o[1] = f2bf(v.y); o[2] = f2bf(v.z); o[3] = f2bf(v.w);
  *(s16x4*)(wb + i) = o;
}

__global__ void zero_counts(int* counts) {
  int i = blockIdx.x * 256 + threadIdx.x;
  if (i < KNODES) counts[i] = 0;
}

__global__ void hist_kernel(const int* __restrict__ ei, int* counts) {
  int i = blockIdx.x * 256 + threadIdx.x;
  if (i < NETOT) {
    int dst = (i < NEDGE) ? ei[NEDGE + i] : (i - NEDGE);
    atomicAdd(&counts[dst], 1);
  }
}

__global__ void scan_kernel(const int* __restrict__ counts, int* offs, int* cursor) {
  __shared__ int tmp[1024];
  const int t = threadIdx.x;
  const int base = t * 4;
  int c0 = counts[base], c1 = counts[base + 1], c2 = counts[base + 2], c3 = counts[base + 3];
  const int s = c0 + c1 + c2 + c3;
  tmp[t] = s;
  __syncthreads();
  for (int off = 1; off < 1024; off <<= 1) {
    int v = (t >= off) ? tmp[t - off] : 0;
    __syncthreads();
    tmp[t] += v;
    __syncthreads();
  }
  int o = tmp[t] - s;
  offs[base] = o; cursor[base] = o; o += c0;
  offs[base + 1] = o; cursor[base + 1] = o; o += c1;
  offs[base + 2] = o; cursor[base + 2] = o; o += c2;
  offs[base + 3] = o; cursor[base + 3] = o; o += c3;
  if (t == 1023) offs[KNODES] = o;
}

__global__ void scatter_kernel(const int* __restrict__ ei, int* cursor, int* __restrict__ csr) {
  int i = blockIdx.x * 256 + threadIdx.x;
  if (i < NETOT) {
    int src, dst;
    if (i < NEDGE) { src = ei[i]; dst = ei[NEDGE + i]; }
    else           { src = dst = i - NEDGE; }
    int pos = atomicAdd(&cursor[dst], 1);
    csr[pos] = src;
  }
}

__global__ __launch_bounds__(256) void gat_aggregate(
    const float* __restrict__ h, const float* __restrict__ as_g, const float* __restrict__ ad_g,
    const int* __restrict__ offs, const int* __restrict__ csr,
    const float* __restrict__ gat_b, float* __restrict__ out) {
  __shared__ float ad_s[SEQL];
  __shared__ float denom[SEQL];
  const int t = threadIdx.x;
  const int n = blockIdx.x;
  if (t < SEQL) { ad_s[t] = ad_g[n * SEQL + t]; denom[t] = 0.f; }
  __syncthreads();
  const int beg = offs[n], end = offs[n + 1];

  for (int e0 = beg; e0 < end; e0 += 8) {
    const int e = e0 + (t >> 5);
    if (e < end) {
      const int src = csr[e];
      const int l = t & 31;
      float v = as_g[src * SEQL + l] + ad_s[l];
      v = v > 0.f ? v : 0.2f * v;
      atomicAdd(&denom[l], expf(v));
    }
  }
  __syncthreads();

  const int d = t & 127, lh = t >> 7;
  float acc[16], invd[16], adv[16];
#pragma unroll
  for (int j = 0; j < 16; ++j) {
    acc[j] = 0.f;
    invd[j] = 1.f / (denom[lh * 16 + j] + 1e-16f);
    adv[j] = ad_s[lh * 16 + j];
  }
  for (int e = beg; e < end; ++e) {
    const int src = csr[e];
    const float* hrow = h + (size_t)src * (SEQL * DM) + d;
    const float* asrow = as_g + src * SEQL;
#pragma unroll
    for (int j = 0; j < 16; ++j) {
      const int l = lh * 16 + j;
      float v = asrow[l] + adv[j];
      v = v > 0.f ? v : 0.2f * v;
      acc[j] += expf(v) * invd[j] * hrow[l * DM];
    }
  }
  const float bd = gat_b[d];
#pragma unroll
  for (int j = 0; j < 16; ++j)
    out[(size_t)n * (SEQL * DM) + (lh * 16 + j) * DM + d] = acc[j] + bd;
}

extern "C" void kernel_launch(void* const* d_in, const int* in_sizes, int n_in,
                              void* d_out, int out_size, void* d_ws, size_t ws_size,
                              hipStream_t stream) {
  const float* x       = (const float*)d_in[0];
  const int* ei        = (const int*)d_in[1];
  const float* ln1_g   = (const float*)d_in[2];
  const float* ln1_b   = (const float*)d_in[3];
  const float* qkv_w   = (const float*)d_in[4];
  const float* qkv_b   = (const float*)d_in[5];
  const float* out_w   = (const float*)d_in[6];
  const float* out_b   = (const float*)d_in[7];
  const float* ln2_g   = (const float*)d_in[8];
  const float* ln2_b   = (const float*)d_in[9];
  const float* ff1_w   = (const float*)d_in[10];
  const float* ff1_b   = (const float*)d_in[11];
  const float* ff2_w   = (const float*)d_in[12];
  const float* ff2_b   = (const float*)d_in[13];
  const float* gat_w   = (const float*)d_in[14];
  const float* att_src = (const float*)d_in[15];
  const float* att_dst = (const float*)d_in[16];
  const float* gat_b   = (const float*)d_in[17];
  float* out = (float*)d_out;

  float* h    = (float*)d_ws;                     // 16777216 floats
  float* as_g = h + (size_t)KNODES * SEQL * DM;   // 131072
  float* ad_g = as_g + KNODES * SEQL;             // 131072
  int* counts = (int*)(ad_g + KNODES * SEQL);     // 4096
  int* offs   = counts + KNODES;                  // 4097
  int* cursor = offs + KNODES + 1;                // 4096
  int* csr    = cursor + KNODES;                  // 69632
  size_t wofs = (size_t)((char*)(csr + NETOT) - (char*)d_ws);
  wofs = (wofs + 15) & ~(size_t)15;
  short* wb = (short*)((char*)d_ws + wofs);       // 212992 shorts (426 KB)
  const short* qkv_wb = wb;
  const short* out_wb = wb + 49152;
  const short* ff1_wb = wb + 65536;
  const short* ff2_wb = wb + 131072;
  const short* gat_wb = wb + 196608;

  cvt_weights<<<208, 256, 0, stream>>>(qkv_w, out_w, ff1_w, ff2_w, gat_w, wb);
  zero_counts<<<(KNODES + 255) / 256, 256, 0, stream>>>(counts);
  hist_kernel<<<(NETOT + 255) / 256, 256, 0, stream>>>(ei, counts);
  scan_kernel<<<1, 1024, 0, stream>>>(counts, offs, cursor);
  scatter_kernel<<<(NETOT + 255) / 256, 256, 0, stream>>>(ei, cursor, csr);
  temporal_kernel<<<KNODES, 256, 0, stream>>>(
      x, ln1_g, ln1_b, qkv_wb, qkv_b, out_wb, out_b, ln2_g, ln2_b,
      ff1_wb, ff1_b, ff2_wb, ff2_b, gat_wb, att_src, att_dst, h, as_g, ad_g);
  gat_aggregate<<<KNODES, 256, 0, stream>>>(h, as_g, ad_g, offs, csr, gat_b, out);
}

// Round 4
// 459.228 us; speedup vs baseline: 7.3399x; 1.2841x over previous
//
#include <hip/hip_runtime.h>

#define KNODES 4096
#define SEQL 32
#define DM 128
#define DFF 512
#define NEDGE 65536
#define NETOT (NEDGE + KNODES)

typedef float f32x4 __attribute__((ext_vector_type(4)));
typedef short s16x8 __attribute__((ext_vector_type(8)));
typedef short s16x4 __attribute__((ext_vector_type(4)));

#define MFMA16(a, b, c) __builtin_amdgcn_mfma_f32_16x16x32_bf16(a, b, c, 0, 0, 0)

__device__ __forceinline__ short f2bf(float f) {
  union { float f; unsigned u; } v; v.f = f;
  unsigned r = (v.u + 0x7FFFu + ((v.u >> 16) & 1u)) >> 16;
  return (short)r;
}

__device__ __forceinline__ float gelu_exact(float v) {
  return 0.5f * v * (1.f + erff(v * 0.70710678118654752440f));
}

// LayerNorm XF[32][132] fp32 -> AB[32][136] bf16. 8 lanes per row (consecutive).
__device__ __forceinline__ void ln_to_bf16(const float* XF, short* AB,
                                           const float* __restrict__ g,
                                           const float* __restrict__ b,
                                           int r8, int c16) {
  const float* xr = XF + r8 * 132 + c16;
  float v[16]; float s = 0.f, ss = 0.f;
#pragma unroll
  for (int i = 0; i < 16; ++i) { v[i] = xr[i]; s += v[i]; ss += v[i] * v[i]; }
  s += __shfl_xor(s, 1); ss += __shfl_xor(ss, 1);
  s += __shfl_xor(s, 2); ss += __shfl_xor(ss, 2);
  s += __shfl_xor(s, 4); ss += __shfl_xor(ss, 4);
  const float mean = s * (1.f / 128.f);
  const float var = ss * (1.f / 128.f) - mean * mean;
  const float rs = rsqrtf(var + 1e-5f);
  const float* gp = g + c16; const float* bp = b + c16;
  short o[16];
#pragma unroll
  for (int i = 0; i < 16; ++i) o[i] = f2bf((v[i] - mean) * rs * gp[i] + bp[i]);
  s16x8* dst = (s16x8*)(AB + r8 * 136 + c16);
  dst[0] = *(s16x8*)o; dst[1] = *(s16x8*)(o + 8);
}

// LDS map (bytes), total 53248 -> 3 blocks/CU (see round-3 notes).
__global__ __launch_bounds__(256, 3) void temporal_kernel(
    const float* __restrict__ x,
    const float* __restrict__ ln1_g, const float* __restrict__ ln1_b,
    const short* __restrict__ qkv_wb, const float* __restrict__ qkv_b,
    const short* __restrict__ out_wb, const float* __restrict__ out_b,
    const float* __restrict__ ln2_g, const float* __restrict__ ln2_b,
    const short* __restrict__ ff1_wb, const float* __restrict__ ff1_b,
    const short* __restrict__ ff2_wb, const float* __restrict__ ff2_b,
    const short* __restrict__ gat_wb,
    const float* __restrict__ att_src, const float* __restrict__ att_dst,
    short* __restrict__ h_out, float* __restrict__ as_out, float* __restrict__ ad_out) {
  __shared__ __align__(16) char smem[53248];
  float* XF = (float*)smem;
  short* AB = (short*)(smem + 16896);
  float* Sf = (float*)(smem + 16896);
  short* Pb = (short*)(smem + 21504);
  short* Qb = (short*)(smem + 25600);
  short* Kb = (short*)(smem + 34304);
  short* Fb = (short*)(smem + 25600);
  short* Vt = (short*)(smem + 43008);

  const int t = threadIdx.x;
  const int w = t >> 6;
  const int lane = t & 63;
  const int q = lane >> 4, c = lane & 15;
  const int n = blockIdx.x;
  const int r8 = t >> 3, c16 = (t & 7) * 16, c4 = (t & 7) * 4;

  // ---- load x -> XF (fp32)
  {
    const float4* s4 = (const float4*)(x + (size_t)n * (SEQL * DM) + r8 * DM + c16);
    float4* d4 = (float4*)(XF + r8 * 132 + c16);
    d4[0] = s4[0]; d4[1] = s4[1]; d4[2] = s4[2]; d4[3] = s4[3];
  }
  __syncthreads();

  // ---- LN1 -> AB
  ln_to_bf16(XF, AB, ln1_g, ln1_b, r8, c16);
  __syncthreads();

  // ---- QKV GEMM: [32x128] @ [128x384]^T. 24 N-tiles, 6 per wave.
  {
    s16x8 a[2][4];
#pragma unroll
    for (int mt = 0; mt < 2; ++mt)
#pragma unroll
      for (int kt = 0; kt < 4; ++kt)
        a[mt][kt] = *(const s16x8*)(AB + (mt * 16 + c) * 136 + kt * 32 + q * 8);
    for (int ii = 0; ii < 6; ++ii) {
      const int n0 = (w * 6 + ii) * 16;
      const short* wp = qkv_wb + (n0 + c) * DM + q * 8;
      s16x8 bf[4];
#pragma unroll
      for (int kt = 0; kt < 4; ++kt) bf[kt] = *(const s16x8*)(wp + kt * 32);
      f32x4 acc0 = {0.f, 0.f, 0.f, 0.f}, acc1 = {0.f, 0.f, 0.f, 0.f};
#pragma unroll
      for (int kt = 0; kt < 4; ++kt) {
        acc0 = MFMA16(a[0][kt], bf[kt], acc0);
        acc1 = MFMA16(a[1][kt], bf[kt], acc1);
      }
      const float bias = qkv_b[n0 + c];
      if (n0 < 128) {            // Q -> Qb row-major
#pragma unroll
        for (int i = 0; i < 4; ++i) {
          Qb[(q * 4 + i) * 136 + n0 + c] = f2bf(acc0[i] + bias);
          Qb[(16 + q * 4 + i) * 136 + n0 + c] = f2bf(acc1[i] + bias);
        }
      } else if (n0 < 256) {     // K -> Kb row-major
        const int cc = n0 - 128 + c;
#pragma unroll
        for (int i = 0; i < 4; ++i) {
          Kb[(q * 4 + i) * 136 + cc] = f2bf(acc0[i] + bias);
          Kb[(16 + q * 4 + i) * 136 + cc] = f2bf(acc1[i] + bias);
        }
      } else {                   // V -> Vt[d][j] transposed (packed b64 writes)
        const int d = n0 - 256 + c;
        s16x4 p0, p1;
#pragma unroll
        for (int i = 0; i < 4; ++i) { p0[i] = f2bf(acc0[i] + bias); p1[i] = f2bf(acc1[i] + bias); }
        *(s16x4*)(Vt + d * 40 + q * 4) = p0;
        *(s16x4*)(Vt + d * 40 + 16 + q * 4) = p1;
      }
    }
  }
  __syncthreads();

  // ---- scores S = Q K^T / sqrt(128). One 16x16 tile per wave.
  {
    const int mt = w & 1, nt = w >> 1;
    s16x8 aq[4], bk[4];
#pragma unroll
    for (int kt = 0; kt < 4; ++kt) {
      aq[kt] = *(const s16x8*)(Qb + (mt * 16 + c) * 136 + kt * 32 + q * 8);
      bk[kt] = *(const s16x8*)(Kb + (nt * 16 + c) * 136 + kt * 32 + q * 8);
    }
    f32x4 acc = {0.f, 0.f, 0.f, 0.f};
#pragma unroll
    for (int kt = 0; kt < 4; ++kt) acc = MFMA16(aq[kt], bk[kt], acc);
#pragma unroll
    for (int i = 0; i < 4; ++i)
      Sf[(mt * 16 + q * 4 + i) * 36 + nt * 16 + c] = acc[i] * 0.08838834764831845f;
  }
  __syncthreads();

  // ---- softmax rows of Sf -> Pb (bf16, A-layout ready)
  {
    float4 sv = *(const float4*)(Sf + r8 * 36 + c4);
    float mx = fmaxf(fmaxf(sv.x, sv.y), fmaxf(sv.z, sv.w));
    mx = fmaxf(mx, __shfl_xor(mx, 1));
    mx = fmaxf(mx, __shfl_xor(mx, 2));
    mx = fmaxf(mx, __shfl_xor(mx, 4));
    float e0 = expf(sv.x - mx), e1 = expf(sv.y - mx), e2 = expf(sv.z - mx), e3 = expf(sv.w - mx);
    float sum = e0 + e1 + e2 + e3;
    sum += __shfl_xor(sum, 1);
    sum += __shfl_xor(sum, 2);
    sum += __shfl_xor(sum, 4);
    const float inv = 1.f / sum;
    s16x4 pw; pw[0] = f2bf(e0 * inv); pw[1] = f2bf(e1 * inv); pw[2] = f2bf(e2 * inv); pw[3] = f2bf(e3 * inv);
    *(s16x4*)(Pb + r8 * 40 + c4) = pw;
  }
  __syncthreads();

  // ---- attn = P @ V  (K=32, one k-tile). 2 d-tiles per wave -> Qb (attn).
  {
    s16x8 ap0 = *(const s16x8*)(Pb + c * 40 + q * 8);
    s16x8 ap1 = *(const s16x8*)(Pb + (16 + c) * 40 + q * 8);
#pragma unroll
    for (int ii = 0; ii < 2; ++ii) {
      const int d0 = (w * 2 + ii) * 16;
      s16x8 bv = *(const s16x8*)(Vt + (d0 + c) * 40 + q * 8);
      f32x4 acc0 = {0.f, 0.f, 0.f, 0.f}, acc1 = {0.f, 0.f, 0.f, 0.f};
      acc0 = MFMA16(ap0, bv, acc0);
      acc1 = MFMA16(ap1, bv, acc1);
#pragma unroll
      for (int i = 0; i < 4; ++i) {
        Qb[(q * 4 + i) * 136 + d0 + c] = f2bf(acc0[i]);
        Qb[(16 + q * 4 + i) * 136 + d0 + c] = f2bf(acc1[i]);
      }
    }
  }
  __syncthreads();

  // ---- proj: XF += attn @ out_w^T + out_b
  {
    s16x8 aa[2][4];
#pragma unroll
    for (int mt = 0; mt < 2; ++mt)
#pragma unroll
      for (int kt = 0; kt < 4; ++kt)
        aa[mt][kt] = *(const s16x8*)(Qb + (mt * 16 + c) * 136 + kt * 32 + q * 8);
#pragma unroll
    for (int ii = 0; ii < 2; ++ii) {
      const int n0 = (w * 2 + ii) * 16;
      const short* wp = out_wb + (n0 + c) * DM + q * 8;
      s16x8 bf[4];
#pragma unroll
      for (int kt = 0; kt < 4; ++kt) bf[kt] = *(const s16x8*)(wp + kt * 32);
      f32x4 acc0 = {0.f, 0.f, 0.f, 0.f}, acc1 = {0.f, 0.f, 0.f, 0.f};
#pragma unroll
      for (int kt = 0; kt < 4; ++kt) {
        acc0 = MFMA16(aa[0][kt], bf[kt], acc0);
        acc1 = MFMA16(aa[1][kt], bf[kt], acc1);
      }
      const float bias = out_b[n0 + c];
#pragma unroll
      for (int i = 0; i < 4; ++i) {
        XF[(q * 4 + i) * 132 + n0 + c] += acc0[i] + bias;
        XF[(16 + q * 4 + i) * 132 + n0 + c] += acc1[i] + bias;
      }
    }
  }
  __syncthreads();

  // ---- LN2 -> AB
  ln_to_bf16(XF, AB, ln2_g, ln2_b, r8, c16);
  __syncthreads();

  // ---- FFN (two 256-col chunks through Fb), FFN2 accumulates in regs
  {
    s16x8 af[2][4];
#pragma unroll
    for (int mt = 0; mt < 2; ++mt)
#pragma unroll
      for (int kt = 0; kt < 4; ++kt)
        af[mt][kt] = *(const s16x8*)(AB + (mt * 16 + c) * 136 + kt * 32 + q * 8);
    f32x4 facc[2][2];
#pragma unroll
    for (int mt = 0; mt < 2; ++mt)
#pragma unroll
      for (int ii = 0; ii < 2; ++ii) facc[mt][ii] = (f32x4){0.f, 0.f, 0.f, 0.f};

    for (int ch = 0; ch < 2; ++ch) {
      // FFN1: 4 n-tiles per wave -> gelu -> Fb
#pragma unroll
      for (int ii = 0; ii < 4; ++ii) {
        const int ntl = w * 4 + ii;            // chunk-local tile 0..15
        const int n0g = ch * 256 + ntl * 16;   // global ff1 row
        const short* wp = ff1_wb + (n0g + c) * DM + q * 8;
        s16x8 bf[4];
#pragma unroll
        for (int kt = 0; kt < 4; ++kt) bf[kt] = *(const s16x8*)(wp + kt * 32);
        f32x4 acc0 = {0.f, 0.f, 0.f, 0.f}, acc1 = {0.f, 0.f, 0.f, 0.f};
#pragma unroll
        for (int kt = 0; kt < 4; ++kt) {
          acc0 = MFMA16(af[0][kt], bf[kt], acc0);
          acc1 = MFMA16(af[1][kt], bf[kt], acc1);
        }
        const float bias = ff1_b[n0g + c];
#pragma unroll
        for (int i = 0; i < 4; ++i) {
          Fb[(q * 4 + i) * 264 + ntl * 16 + c] = f2bf(gelu_exact(acc0[i] + bias));
          Fb[(16 + q * 4 + i) * 264 + ntl * 16 + c] = f2bf(gelu_exact(acc1[i] + bias));
        }
      }
      __syncthreads();
      // FFN2 partial over this chunk's K=256
      {
        s16x8 a2[2][8];
#pragma unroll
        for (int mt = 0; mt < 2; ++mt)
#pragma unroll
          for (int kt = 0; kt < 8; ++kt)
            a2[mt][kt] = *(const s16x8*)(Fb + (mt * 16 + c) * 264 + kt * 32 + q * 8);
#pragma unroll
        for (int ii = 0; ii < 2; ++ii) {
          const int n0 = (w * 2 + ii) * 16;
          const short* wp = ff2_wb + (n0 + c) * DFF + ch * 256 + q * 8;
#pragma unroll
          for (int kt = 0; kt < 8; ++kt) {
            s16x8 bf = *(const s16x8*)(wp + kt * 32);
            facc[0][ii] = MFMA16(a2[0][kt], bf, facc[0][ii]);
            facc[1][ii] = MFMA16(a2[1][kt], bf, facc[1][ii]);
          }
        }
      }
      __syncthreads();
    }
    // epilogue fused with xt->bf16: AB = bf16(XF + facc + ff2_b)
#pragma unroll
    for (int ii = 0; ii < 2; ++ii) {
      const int n0 = (w * 2 + ii) * 16;
      const float bias = ff2_b[n0 + c];
#pragma unroll
      for (int i = 0; i < 4; ++i) {
        const int r0 = q * 4 + i, r1 = 16 + q * 4 + i;
        AB[r0 * 136 + n0 + c] = f2bf(XF[r0 * 132 + n0 + c] + facc[0][ii][i] + bias);
        AB[r1 * 136 + n0 + c] = f2bf(XF[r1 * 132 + n0 + c] + facc[1][ii][i] + bias);
      }
    }
  }
  __syncthreads();

  // ---- GAT projection h = xt @ gat_w^T -> global h_out (bf16) + XF scratch (fp32)
  {
    s16x8 ag[2][4];
#pragma unroll
    for (int mt = 0; mt < 2; ++mt)
#pragma unroll
      for (int kt = 0; kt < 4; ++kt)
        ag[mt][kt] = *(const s16x8*)(AB + (mt * 16 + c) * 136 + kt * 32 + q * 8);
#pragma unroll
    for (int ii = 0; ii < 2; ++ii) {
      const int n0 = (w * 2 + ii) * 16;
      const short* wp = gat_wb + (n0 + c) * DM + q * 8;
      s16x8 bf[4];
#pragma unroll
      for (int kt = 0; kt < 4; ++kt) bf[kt] = *(const s16x8*)(wp + kt * 32);
      f32x4 acc0 = {0.f, 0.f, 0.f, 0.f}, acc1 = {0.f, 0.f, 0.f, 0.f};
#pragma unroll
      for (int kt = 0; kt < 4; ++kt) {
        acc0 = MFMA16(ag[0][kt], bf[kt], acc0);
        acc1 = MFMA16(ag[1][kt], bf[kt], acc1);
      }
#pragma unroll
      for (int i = 0; i < 4; ++i) {
        const int r0 = q * 4 + i, r1 = 16 + q * 4 + i;
        h_out[((size_t)n * SEQL + r0) * DM + n0 + c] = f2bf(acc0[i]);
        h_out[((size_t)n * SEQL + r1) * DM + n0 + c] = f2bf(acc1[i]);
        XF[r0 * 132 + n0 + c] = acc0[i];
        XF[r1 * 132 + n0 + c] = acc1[i];
      }
    }
  }
  __syncthreads();

  // ---- a_s / a_d (fp32 h from XF)
  if (t < 64) {
    const int row = t & 31;
    const float* vec = (t < 32) ? att_src : att_dst;
    const float* hr = XF + row * 132;
    float s = 0.f;
#pragma unroll
    for (int d = 0; d < DM; d += 4)
      s += hr[d] * vec[d] + hr[d + 1] * vec[d + 1] + hr[d + 2] * vec[d + 2] + hr[d + 3] * vec[d + 3];
    if (t < 32) as_out[n * SEQL + row] = s;
    else        ad_out[n * SEQL + row] = s;
  }
}

// fp32 -> bf16 weight conversion, all 5 arrays into one contiguous buffer.
__global__ void cvt_weights(const float* __restrict__ qkv_w, const float* __restrict__ out_w,
                            const float* __restrict__ ff1_w, const float* __restrict__ ff2_w,
                            const float* __restrict__ gat_w, short* __restrict__ wb) {
  const int i = (blockIdx.x * 256 + threadIdx.x) * 4;
  if (i >= 212992) return;
  const float* src; int off;
  if (i < 49152)       { src = qkv_w; off = i; }
  else if (i < 65536)  { src = out_w; off = i - 49152; }
  else if (i < 131072) { src = ff1_w; off = i - 65536; }
  else if (i < 196608) { src = ff2_w; off = i - 131072; }
  else                 { src = gat_w; off = i - 196608; }
  const float4 v = *(const float4*)(src + off);
  s16x4 o; o[0] = f2bf(v.x); o[1] = f2bf(v.y); o[2] = f2bf(v.z); o[3] = f2bf(v.w);
  *(s16x4*)(wb + i) = o;
}

__global__ void zero_counts(int* counts) {
  int i = blockIdx.x * 256 + threadIdx.x;
  if (i < KNODES) counts[i] = 0;
}

__global__ void hist_kernel(const int* __restrict__ ei, int* counts) {
  int i = blockIdx.x * 256 + threadIdx.x;
  if (i < NETOT) {
    int dst = (i < NEDGE) ? ei[NEDGE + i] : (i - NEDGE);
    atomicAdd(&counts[dst], 1);
  }
}

__global__ void scan_kernel(const int* __restrict__ counts, int* offs, int* cursor) {
  __shared__ int tmp[1024];
  const int t = threadIdx.x;
  const int base = t * 4;
  int c0 = counts[base], c1 = counts[base + 1], c2 = counts[base + 2], c3 = counts[base + 3];
  const int s = c0 + c1 + c2 + c3;
  tmp[t] = s;
  __syncthreads();
  for (int off = 1; off < 1024; off <<= 1) {
    int v = (t >= off) ? tmp[t - off] : 0;
    __syncthreads();
    tmp[t] += v;
    __syncthreads();
  }
  int o = tmp[t] - s;
  offs[base] = o; cursor[base] = o; o += c0;
  offs[base + 1] = o; cursor[base + 1] = o; o += c1;
  offs[base + 2] = o; cursor[base + 2] = o; o += c2;
  offs[base + 3] = o; cursor[base + 3] = o; o += c3;
  if (t == 1023) offs[KNODES] = o;
}

__global__ void scatter_kernel(const int* __restrict__ ei, int* cursor, int* __restrict__ csr) {
  int i = blockIdx.x * 256 + threadIdx.x;
  if (i < NETOT) {
    int src, dst;
    if (i < NEDGE) { src = ei[i]; dst = ei[NEDGE + i]; }
    else           { src = dst = i - NEDGE; }
    int pos = atomicAdd(&cursor[dst], 1);
    csr[pos] = src;
  }
}

// One block per dst node. Single pass: unnormalized accumulate + deferred divide.
// Edge-weights computed ONCE per (edge, l) into LDS, broadcast in the fma loop.
#define ECH 32
__global__ __launch_bounds__(256) void gat_aggregate(
    const short* __restrict__ h, const float* __restrict__ as_g, const float* __restrict__ ad_g,
    const int* __restrict__ offs, const int* __restrict__ csr,
    const float* __restrict__ gat_b, float* __restrict__ out) {
  __shared__ float ad_s[SEQL];
  __shared__ float ew[ECH * 33];    // [slot][l], pitch 33
  __shared__ int   srcs[ECH];
  __shared__ float dred[32 * 32];   // [l][slot] partial denoms
  __shared__ float invd[SEQL];

  const int t = threadIdx.x;
  const int n = blockIdx.x;
  if (t < SEQL) ad_s[t] = ad_g[n * SEQL + t];
  __syncthreads();
  const int beg = offs[n], end = offs[n + 1];

  // phase-A roles: slot s (edge within chunk), lq -> 4 l's
  const int s = t >> 3, lq = t & 7;
  float dpart[4] = {0.f, 0.f, 0.f, 0.f};

  // phase-B roles: d pair = lane2*2, l group = wave id (uniform per wave)
  const int lane2 = t & 63;
  const int lg = t >> 6;
  float acc[8][2];
#pragma unroll
  for (int j = 0; j < 8; ++j) { acc[j][0] = 0.f; acc[j][1] = 0.f; }

  for (int cb = beg; cb < end; cb += ECH) {
    const int cnt = min(ECH, end - cb);
    // ---- phase A: ew[s][l] = exp(leaky(as[src,l]+ad[n,l])), denom partials
    if (s < cnt) {
      const int src = csr[cb + s];
      if (lq == 0) srcs[s] = src;
      const float4 av = *(const float4*)(as_g + src * SEQL + lq * 4);
      float vv[4] = {av.x, av.y, av.z, av.w};
#pragma unroll
      for (int i = 0; i < 4; ++i) {
        float v = vv[i] + ad_s[lq * 4 + i];
        v = v > 0.f ? v : 0.2f * v;
        const float e = __expf(v);
        ew[s * 33 + lq * 4 + i] = e;
        dpart[i] += e;
      }
    }
    __syncthreads();
    // ---- phase B: acc += ew * h[src]  (ew/srcs are wave-uniform -> broadcast)
    for (int ss = 0; ss < cnt; ++ss) {
      const int src = srcs[ss];
      const short* hrow = h + (size_t)src * (SEQL * DM) + lg * 8 * DM + lane2 * 2;
      const float* ewp = ew + ss * 33 + lg * 8;
#pragma unroll
      for (int j = 0; j < 8; ++j) {
        const unsigned u = *(const unsigned*)(hrow + j * DM);
        const float h0 = __uint_as_float(u << 16);
        const float h1 = __uint_as_float(u & 0xFFFF0000u);
        const float wgt = ewp[j];
        acc[j][0] += wgt * h0;
        acc[j][1] += wgt * h1;
      }
    }
    __syncthreads();
  }

  // ---- denominator reduce: dred[l][slot] -> invd[l]
#pragma unroll
  for (int i = 0; i < 4; ++i) dred[(lq * 4 + i) * 32 + s] = dpart[i];
  __syncthreads();
  if (t < SEQL) {
    float sum = 0.f;
#pragma unroll
    for (int s2 = 0; s2 < 32; ++s2) sum += dred[t * 32 + s2];
    invd[t] = 1.f / (sum + 1e-16f);
  }
  __syncthreads();

  // ---- write out: out[n,l,d] = acc/denom + bias
  const float b0 = gat_b[lane2 * 2], b1 = gat_b[lane2 * 2 + 1];
#pragma unroll
  for (int j = 0; j < 8; ++j) {
    const int l = lg * 8 + j;
    const float iv = invd[l];
    float2 o;
    o.x = acc[j][0] * iv + b0;
    o.y = acc[j][1] * iv + b1;
    *(float2*)(out + (size_t)n * (SEQL * DM) + l * DM + lane2 * 2) = o;
  }
}

extern "C" void kernel_launch(void* const* d_in, const int* in_sizes, int n_in,
                              void* d_out, int out_size, void* d_ws, size_t ws_size,
                              hipStream_t stream) {
  const float* x       = (const float*)d_in[0];
  const int* ei        = (const int*)d_in[1];
  const float* ln1_g   = (const float*)d_in[2];
  const float* ln1_b   = (const float*)d_in[3];
  const float* qkv_w   = (const float*)d_in[4];
  const float* qkv_b   = (const float*)d_in[5];
  const float* out_w   = (const float*)d_in[6];
  const float* out_b   = (const float*)d_in[7];
  const float* ln2_g   = (const float*)d_in[8];
  const float* ln2_b   = (const float*)d_in[9];
  const float* ff1_w   = (const float*)d_in[10];
  const float* ff1_b   = (const float*)d_in[11];
  const float* ff2_w   = (const float*)d_in[12];
  const float* ff2_b   = (const float*)d_in[13];
  const float* gat_w   = (const float*)d_in[14];
  const float* att_src = (const float*)d_in[15];
  const float* att_dst = (const float*)d_in[16];
  const float* gat_b   = (const float*)d_in[17];
  float* out = (float*)d_out;

  // workspace layout
  short* h    = (short*)d_ws;                           // 16777216 shorts (bf16, 32 MB)
  float* as_g = (float*)(h + (size_t)KNODES * SEQL * DM); // 131072 floats
  float* ad_g = as_g + KNODES * SEQL;                   // 131072
  int* counts = (int*)(ad_g + KNODES * SEQL);           // 4096
  int* offs   = counts + KNODES;                        // 4097
  int* cursor = offs + KNODES + 1;                      // 4096
  int* csr    = cursor + KNODES;                        // 69632
  size_t wofs = (size_t)((char*)(csr + NETOT) - (char*)d_ws);
  wofs = (wofs + 15) & ~(size_t)15;
  short* wb = (short*)((char*)d_ws + wofs);             // 212992 shorts
  const short* qkv_wb = wb;
  const short* out_wb = wb + 49152;
  const short* ff1_wb = wb + 65536;
  const short* ff2_wb = wb + 131072;
  const short* gat_wb = wb + 196608;

  cvt_weights<<<208, 256, 0, stream>>>(qkv_w, out_w, ff1_w, ff2_w, gat_w, wb);
  zero_counts<<<(KNODES + 255) / 256, 256, 0, stream>>>(counts);
  hist_kernel<<<(NETOT + 255) / 256, 256, 0, stream>>>(ei, counts);
  scan_kernel<<<1, 1024, 0, stream>>>(counts, offs, cursor);
  scatter_kernel<<<(NETOT + 255) / 256, 256, 0, stream>>>(ei, cursor, csr);
  temporal_kernel<<<KNODES, 256, 0, stream>>>(
      x, ln1_g, ln1_b, qkv_wb, qkv_b, out_wb, out_b, ln2_g, ln2_b,
      ff1_wb, ff1_b, ff2_wb, ff2_b, gat_wb, att_src, att_dst, h, as_g, ad_g);
  gat_aggregate<<<KNODES, 256, 0, stream>>>(h, as_g, ad_g, offs, csr, gat_b, out);
}